// Round 8
// baseline (1425.474 us; speedup 1.0000x reference)
//
#include <hip/hip_runtime.h>
#include <hip/hip_bf16.h>

typedef _Float16 f16x8 __attribute__((ext_vector_type(8)));
typedef _Float16 f16x4 __attribute__((ext_vector_type(4)));
typedef float f32x4 __attribute__((ext_vector_type(4)));

#define B_SZ 64
#define T_SZ 2048
#define D_SZ 300
#define KP 320                   // padded K for W
#define NP 640                   // combined N (z: 0..299, o: 320..619)
#define NCHUNK 64
#define CLEN 32                  // T / NCHUNK
#define NBLK (B_SZ * NCHUNK)     // 4096 blocks = (nc, b), nc-major

__device__ __forceinline__ float fast_tanh(float x) {
    float e = __expf(2.0f * x);
    return 1.0f - 2.0f * __builtin_amdgcn_rcpf(e + 1.0f);
}

__device__ __forceinline__ f16x8 cvt8(f32x4 v0, f32x4 v1) {
    f16x8 r;
    r[0] = (_Float16)v0[0]; r[1] = (_Float16)v0[1];
    r[2] = (_Float16)v0[2]; r[3] = (_Float16)v0[3];
    r[4] = (_Float16)v1[0]; r[5] = (_Float16)v1[1];
    r[6] = (_Float16)v1[2]; r[7] = (_Float16)v1[3];
    return r;
}

// ---- pack Wz/Wo fp32 [300,300] -> combined fp16 [640,320], zero-padded ----
// k-pad zeros (300..319) also nullify garbage/zeroed A tail fragments.
__global__ void pack_w(const float* __restrict__ Wz, const float* __restrict__ Wo,
                       _Float16* __restrict__ W) {
    unsigned int i = blockIdx.x * 256u + threadIdx.x;
    if (i >= NP * KP) return;
    unsigned int n = i / KP;
    unsigned int k = i - n * KP;
    float v = 0.0f;
    if (k < D_SZ) {
        if (n < D_SZ) v = Wz[n * D_SZ + k];
        else if (n >= 320 && n < 320 + D_SZ) v = Wo[(n - 320) * D_SZ + k];
    }
    W[i] = (_Float16)v;
}

__global__ void pack_bias(const float* __restrict__ bz, const float* __restrict__ bo,
                          float* __restrict__ bias) {
    int n = threadIdx.x;
    float v = 0.0f;
    if (n < D_SZ) v = bz[n];
    else if (n >= 320 && n < 320 + D_SZ) v = bo[n - 320];
    bias[n] = v;
}

__global__ void init_flags(int* __restrict__ flags) {
    int i = blockIdx.x * 256 + threadIdx.x;
    if (i < NBLK) flags[i] = 0;
}

// ---- Fully fused: GEMM(z,o) + chunk scan + decoupled lookback + output ----
// Block = (nc, b): rows t in [nc*32, nc*32+32) of batch b.
// Phase G: z,o = tanh(X W^T + bias) for 32 rows x 640 cols -> LDS (f16).
//   A-frags in regs (from fp32 X directly), B streamed from L2-resident W.
//   4 waves (2m x 2n), swapped-operand 16x16x32 f16 MFMA, barrier-free.
// Phase S1: stream gate (store f16 to LDS), compute chunk affine (A, Bc) per d.
// Lookback: publish c_end, spin on predecessor (agent-scope atomics).
// Phase S2: replay chunk with c_in, write h = o*c straight to out.
__global__ __launch_bounds__(256, 2) void fused(const float* __restrict__ X,
                                                const float* __restrict__ gate,
                                                const _Float16* __restrict__ W,
                                                const float* __restrict__ bias,
                                                float* __restrict__ out,
                                                float* __restrict__ prefc,
                                                int* __restrict__ flags) {
    __shared__ _Float16 zo[CLEN][648];   // 41,472 B  (z cols 0..299, o cols 320..619)
    __shared__ _Float16 gl[CLEN][304];   // 19,456 B  (gate, f16)

    const int tid = threadIdx.x;
    const int lane = tid & 63;
    const int wid = tid >> 6;            // 0..3
    const int wm = wid >> 1, wn = wid & 1;
    const int l15 = lane & 15;
    const int kq = lane >> 4;

    const int blk = blockIdx.x;          // nc-major: blk = nc*64 + b
    const int b = blk & 63;
    const int nc = blk >> 6;
    const size_t base_m = (size_t)b * T_SZ + (size_t)nc * CLEN;

    // ---- load A fragments (rows = wm*16 + l15) from fp32 X, cvt to f16 ----
    const int mrow = wm * 16 + l15;      // local t-row 0..31
    const float* xrow = X + (base_m + mrow) * D_SZ;
    f16x8 af[10];
#pragma unroll
    for (int kt = 0; kt < 10; ++kt) {
        int k0 = kt * 32 + kq * 8;
        f32x4 v0 = {}, v1 = {};
        if (k0 < D_SZ)     v0 = *(const f32x4*)(xrow + k0);
        if (k0 + 4 < D_SZ) v1 = *(const f32x4*)(xrow + k0 + 4);
        af[kt] = cvt8(v0, v1);
    }

    // ---- GEMM over 10 bn-subtiles of 64 cols ----
#pragma unroll 1
    for (int bn = 0; bn < 10; ++bn) {
        const _Float16* wr0 = W + (size_t)(bn * 64 + wn * 32 + l15) * KP + kq * 8;
        const _Float16* wr1 = wr0 + (size_t)16 * KP;
        f32x4 acc0 = {}, acc1 = {};
        f16x8 bf0 = *(const f16x8*)wr0;
        f16x8 bf1 = *(const f16x8*)wr1;
#pragma unroll
        for (int kt = 0; kt < 10; ++kt) {
            f16x8 nbf0 = {}, nbf1 = {};
            if (kt < 9) {
                nbf0 = *(const f16x8*)(wr0 + (kt + 1) * 32);
                nbf1 = *(const f16x8*)(wr1 + (kt + 1) * 32);
            }
            acc0 = __builtin_amdgcn_mfma_f32_16x16x32_f16(bf0, af[kt], acc0, 0, 0, 0);
            acc1 = __builtin_amdgcn_mfma_f32_16x16x32_f16(bf1, af[kt], acc1, 0, 0, 0);
            bf0 = nbf0; bf1 = nbf1;
        }
        // epilogue: lane holds n = bn*64 + wn*32 + ns*16 + kq*4 + r at row mrow
        int nb0 = bn * 64 + wn * 32 + kq * 4;
        f32x4 bb0 = *(const f32x4*)&bias[nb0];
        f32x4 bb1 = *(const f32x4*)&bias[nb0 + 16];
        f16x4 v0, v1;
#pragma unroll
        for (int r = 0; r < 4; ++r) {
            v0[r] = (_Float16)fast_tanh(acc0[r] + bb0[r]);
            v1[r] = (_Float16)fast_tanh(acc1[r] + bb1[r]);
        }
        *(f16x4*)&zo[mrow][nb0] = v0;
        *(f16x4*)&zo[mrow][nb0 + 16] = v1;
    }
    __syncthreads();   // zo complete

    // ---- S1: stream gate -> f16 LDS, per-d chunk affine (A, Bc) ----
    const float* gbase = gate + base_m * D_SZ;
    const int d1 = tid;
    const int d2 = 256 + tid;
    const bool has2 = (tid < D_SZ - 256);   // 44 threads carry a second d
    float A1 = 1.0f, B1 = 0.0f, A2 = 1.0f, B2 = 0.0f;
#pragma unroll 4
    for (int t = 0; t < CLEN; ++t) {
        _Float16 h1 = (_Float16)gbase[(size_t)t * D_SZ + d1];
        gl[t][d1] = h1;
        float g1 = (float)h1;
        float z1 = (float)zo[t][d1];
        A1 *= g1;
        B1 = g1 * B1 + (1.0f - g1) * z1;
        if (has2) {
            _Float16 h2 = (_Float16)gbase[(size_t)t * D_SZ + d2];
            gl[t][d2] = h2;
            float g2 = (float)h2;
            float z2 = (float)zo[t][d2];
            A2 *= g2;
            B2 = g2 * B2 + (1.0f - g2) * z2;
        }
    }

    // ---- decoupled lookback: c_in from predecessor chunk (same b) ----
    float cp1 = 0.0f, cp2 = 0.0f;
    if (nc > 0) {
        if (tid == 0) {
            while (__hip_atomic_load(&flags[blk - 64], __ATOMIC_ACQUIRE,
                                     __HIP_MEMORY_SCOPE_AGENT) == 0)
                __builtin_amdgcn_s_sleep(8);
        }
        __syncthreads();
        cp1 = __hip_atomic_load(&prefc[(size_t)(blk - 64) * 304 + d1],
                                __ATOMIC_RELAXED, __HIP_MEMORY_SCOPE_AGENT);
        if (has2)
            cp2 = __hip_atomic_load(&prefc[(size_t)(blk - 64) * 304 + d2],
                                    __ATOMIC_RELAXED, __HIP_MEMORY_SCOPE_AGENT);
    }
    float ce1 = A1 * cp1 + B1;
    __hip_atomic_store(&prefc[(size_t)blk * 304 + d1], ce1,
                       __ATOMIC_RELAXED, __HIP_MEMORY_SCOPE_AGENT);
    if (has2) {
        float ce2 = A2 * cp2 + B2;
        __hip_atomic_store(&prefc[(size_t)blk * 304 + d2], ce2,
                           __ATOMIC_RELAXED, __HIP_MEMORY_SCOPE_AGENT);
    }
    __threadfence();
    __syncthreads();
    if (tid == 0)
        __hip_atomic_store(&flags[blk], 1, __ATOMIC_RELEASE,
                           __HIP_MEMORY_SCOPE_AGENT);

    // ---- S2: replay with c_in, write h = o * c ----
    float* obase = out + base_m * D_SZ;
    float c1 = cp1, c2 = cp2;
#pragma unroll 4
    for (int t = 0; t < CLEN; ++t) {
        float g1 = (float)gl[t][d1];
        float z1 = (float)zo[t][d1];
        float o1 = (float)zo[t][320 + d1];
        c1 = g1 * c1 + (1.0f - g1) * z1;
        obase[(size_t)t * D_SZ + d1] = o1 * c1;
        if (has2) {
            float g2 = (float)gl[t][d2];
            float z2 = (float)zo[t][d2];
            float o2 = (float)zo[t][320 + d2];
            c2 = g2 * c2 + (1.0f - g2) * z2;
            obase[(size_t)t * D_SZ + d2] = o2 * c2;
        }
    }
}

extern "C" void kernel_launch(void* const* d_in, const int* in_sizes, int n_in,
                              void* d_out, int out_size, void* d_ws, size_t ws_size,
                              hipStream_t stream) {
    const float* gate = (const float*)d_in[0];
    const float* xin  = (const float*)d_in[1];
    const float* Wz   = (const float*)d_in[2];
    const float* bz   = (const float*)d_in[3];
    const float* Wo   = (const float*)d_in[4];
    const float* bo   = (const float*)d_in[5];
    float* out = (float*)d_out;

    char* ws = (char*)d_ws;
    _Float16* Wc   = (_Float16*)(ws);                 // 640*320*2 = 409,600
    float*    bias = (float*)   (ws + 409600ull);     // 2,560
    float*    prefc= (float*)   (ws + 412160ull);     // 4096*304*4 = 4,980,736
    int*      flags= (int*)     (ws + 5392896ull);    // 4096*4 = 16,384

    pack_w<<<(NP * KP + 255) / 256, 256, 0, stream>>>(Wz, Wo, Wc);
    pack_bias<<<1, NP, 0, stream>>>(bz, bo, bias);
    init_flags<<<(NBLK + 255) / 256, 256, 0, stream>>>(flags);

    fused<<<NBLK, 256, 0, stream>>>(xin, gate, Wc, bias, out, prefc, flags);
}

// Round 9
// 302.412 us; speedup vs baseline: 4.7137x; 4.7137x over previous
//
#include <hip/hip_runtime.h>
#include <hip/hip_bf16.h>

typedef _Float16 f16x8 __attribute__((ext_vector_type(8)));
typedef _Float16 f16x4 __attribute__((ext_vector_type(4)));
typedef float f32x4 __attribute__((ext_vector_type(4)));

#define B_SZ 64
#define T_SZ 2048
#define D_SZ 300
#define M_SZ (B_SZ * T_SZ)      // 131072
#define KP 320                   // padded K
#define NP 640                   // padded combined N (z: 0..299, o: 320..619)
#define NCHUNK 32
#define CLEN 64                  // T / NCHUNK

__device__ __forceinline__ void gld_lds16(const void* g, void* l) {
    __builtin_amdgcn_global_load_lds(
        (const __attribute__((address_space(1))) unsigned int*)g,
        (__attribute__((address_space(3))) unsigned int*)l,
        16, 0, 0);
}

__device__ __forceinline__ float fast_tanh(float x) {
    float e = __expf(2.0f * x);
    return 1.0f - 2.0f * __builtin_amdgcn_rcpf(e + 1.0f);
}

// ---- pack X fp32 [M,300] -> fp16 [M,320], vectorized, pad fused ----
__global__ void pack_x(const float* __restrict__ in, _Float16* __restrict__ out) {
    unsigned int i = blockIdx.x * 256u + threadIdx.x;   // grid covers M*80 exactly
    unsigned int row = i / 80;
    unsigned int kq = i - row * 80;
    if (kq < 75) {
        f32x4 v = *(const f32x4*)(in + (size_t)row * D_SZ + kq * 4);
        f16x4 h;
#pragma unroll
        for (int r = 0; r < 4; ++r) h[r] = (_Float16)v[r];
        *(f16x4*)(out + (size_t)row * KP + kq * 4) = h;
    } else {
        f16x4 z = {};
        *(f16x4*)(out + (size_t)row * KP + 300 + (kq - 75) * 4) = z;
    }
}

// ---- pack Wz/Wo fp32 [300,300] -> combined fp16 [640,320], zero-padded ----
__global__ void pack_w(const float* __restrict__ Wz, const float* __restrict__ Wo,
                       _Float16* __restrict__ W) {
    unsigned int i = blockIdx.x * 256u + threadIdx.x;
    if (i >= NP * KP) return;
    unsigned int n = i / KP;
    unsigned int k = i - n * KP;
    float v = 0.0f;
    if (k < D_SZ) {
        if (n < D_SZ) v = Wz[n * D_SZ + k];
        else if (n >= 320 && n < 320 + D_SZ) v = Wo[(n - 320) * D_SZ + k];
    }
    W[i] = (_Float16)v;
}

__global__ void pack_bias(const float* __restrict__ bz, const float* __restrict__ bo,
                          float* __restrict__ bias) {
    int n = threadIdx.x;
    float v = 0.0f;
    if (n < D_SZ) v = bz[n];
    else if (n >= 320 && n < 320 + D_SZ) v = bo[n - 320];
    bias[n] = v;
}

// ---- GEMM: C16[m][n] = tanh( sum_k X[m][k]*W[n][k] + bias[n] ), fp16 out ----
// EXACT R2 structure (measured 121-123 us three times): 256x128 tile, BK=32,
// 8 waves (4x2), gld_lds staging, 2-phase syncthreads loop, swapped MFMA.
// ONLY change: epilogue shuffles each wave's 64x64 tile through LDS so global
// stores are f16x8 FULL 128-B lines (8 instr x 8 full lines vs 16 x 16 partial).
__global__ __launch_bounds__(512) void gemm_zo(const _Float16* __restrict__ X,
                                               const _Float16* __restrict__ W,
                                               const float* __restrict__ bias,
                                               _Float16* __restrict__ C) {
    __shared__ _Float16 As[2][256 * 32];   // 32 KB
    __shared__ _Float16 Bs[2][128 * 32];   // 16 KB

    const int tid = threadIdx.x;
    const int lane = tid & 63;
    const int wid = tid >> 6;              // 0..7
    const int wm = wid >> 1, wn = wid & 1; // 4 x 2 wave grid

    // XCD-aware swizzle (2560 blocks, 2560 % 8 == 0 -> bijective)
    int g = blockIdx.x;
    int s = (g & 7) * (2560 / 8) + (g >> 3);
    int bm = s / 5;          // 512 M-tiles
    int bn = s - bm * 5;     // 5 N-tiles

    f32x4 acc[4][4] = {};

    const int r_in_c = lane >> 2;          // row within 16-row chunk
    const int u_phys = lane & 3;           // 16B unit within 64B row

    auto stage = [&](int buf, int kt) {
        // A: 16 chunks of 16 rows; this wave stages chunks wid, wid+8
#pragma unroll
        for (int j = 0; j < 2; ++j) {
            int c = wid + j * 8;
            int row = c * 16 + r_in_c;
            int ul = u_phys ^ ((row >> 1) & 3);   // inverse-swizzled source unit
            const _Float16* ga = X + ((size_t)(bm * 256 + row) * KP + kt * 32 + ul * 8);
            gld_lds16(ga, &As[buf][c * 512]);
        }
        // B: 8 chunks; this wave stages chunk wid
        {
            int c = wid;
            int row = c * 16 + r_in_c;
            int ul = u_phys ^ ((row >> 1) & 3);
            const _Float16* gb = W + ((size_t)(bn * 128 + row) * KP + kt * 32 + ul * 8);
            gld_lds16(gb, &Bs[buf][c * 512]);
        }
    };

    stage(0, 0);
    __syncthreads();

    const int l15 = lane & 15;
    const int kq = lane >> 4;

    int buf = 0;
#pragma unroll 1
    for (int kt = 0; kt < 10; ++kt) {
        if (kt < 9) stage(buf ^ 1, kt + 1);

        f16x8 bf[4];
#pragma unroll
        for (int ns = 0; ns < 4; ++ns) {
            int row = wn * 64 + ns * 16 + l15;
            int u = kq ^ ((row >> 1) & 3);
            bf[ns] = *(const f16x8*)&Bs[buf][row * 32 + u * 8];
        }
#pragma unroll
        for (int ms = 0; ms < 4; ++ms) {
            int row = wm * 64 + ms * 16 + l15;
            int u = kq ^ ((row >> 1) & 3);
            f16x8 af = *(const f16x8*)&As[buf][row * 32 + u * 8];
#pragma unroll
            for (int ns = 0; ns < 4; ++ns)
                acc[ms][ns] = __builtin_amdgcn_mfma_f32_16x16x32_f16(bf[ns], af, acc[ms][ns], 0, 0, 0);
        }

        __syncthreads();
        buf ^= 1;
    }

    // ---- epilogue: LDS-shuffled, fully-coalesced full-line stores ----
    // swapped layout: value (ms,ns,r) sits at m = mrow0+ms*16+l15,
    //                                     n = ncol0+ns*16+kq*4+r
    __syncthreads();                       // all K-loop LDS reads done; reuse As
    _Float16* et = &As[0][0] + wid * 1024; // [16 rows][64 cols] f16, wave-private

    const int mrow0 = bm * 256 + wm * 64;
    const int ncol0 = bn * 128 + wn * 64;
    const int row8 = lane >> 3;            // 0..7
    const int u8 = lane & 7;               // logical 16B unit within 128B row

    f32x4 b4[4];
#pragma unroll
    for (int ns = 0; ns < 4; ++ns)
        b4[ns] = *(const f32x4*)&bias[ncol0 + ns * 16 + kq * 4];

#pragma unroll
    for (int ms = 0; ms < 4; ++ms) {
#pragma unroll
        for (int ns = 0; ns < 4; ++ns) {
            f16x4 v;
#pragma unroll
            for (int r = 0; r < 4; ++r)
                v[r] = (_Float16)fast_tanh(acc[ms][ns][r] + b4[ns][r]);
            // XOR-swizzled write: logical unit ns*2+(kq>>1), half kq&1
            int up = ((ns << 1) | (kq >> 1)) ^ (l15 & 7);
            *(f16x4*)&et[l15 * 64 + up * 8 + (kq & 1) * 4] = v;
        }
        // read back row-contiguous (unswizzle), store full 128-B lines
#pragma unroll
        for (int j = 0; j < 2; ++j) {
            int rr = row8 + j * 8;
            f16x8 o = *(const f16x8*)&et[rr * 64 + (u8 ^ (rr & 7)) * 8];
            *(f16x8*)&C[(size_t)(mrow0 + ms * 16 + rr) * NP + ncol0 + u8 * 8] = o;
        }
    }
}

// ---- scan phase 1: per (b, chunk, d) compute affine (A = prod g, Bc) ----
__global__ void scan_p1(const float* __restrict__ gate, const _Float16* __restrict__ C,
                        float* __restrict__ Aout, float* __restrict__ Bout) {
    int b = blockIdx.x >> 5;
    int nc = blockIdx.x & 31;
    int d = threadIdx.x;
    if (d >= D_SZ) return;
    size_t base = (size_t)b * T_SZ + (size_t)nc * CLEN;
    const float* gp = gate + base * D_SZ + d;
    const _Float16* zp = C + base * NP + d;
    float A = 1.0f, Bc = 0.0f;
    for (int t = 0; t < CLEN; ++t) {
        float gv = gp[(size_t)t * D_SZ];
        float zv = (float)zp[(size_t)t * NP];
        A *= gv;
        Bc = gv * Bc + (1.0f - gv) * zv;
    }
    int o = (b * NCHUNK + nc) * D_SZ + d;
    Aout[o] = A;
    Bout[o] = Bc;
}

// ---- scan phase 2: sequential scan over the 32 chunk summaries ----
__global__ void scan_p2(const float* __restrict__ A, const float* __restrict__ Bc,
                        float* __restrict__ Cin) {
    int idx = blockIdx.x * 256 + threadIdx.x;
    if (idx >= B_SZ * D_SZ) return;
    int b = idx / D_SZ;
    int d = idx - b * D_SZ;
    float c = 0.0f;
    for (int nc = 0; nc < NCHUNK; ++nc) {
        int o = (b * NCHUNK + nc) * D_SZ + d;
        Cin[o] = c;
        c = A[o] * c + Bc[o];
    }
}

// ---- scan phase 3: replay chunk with correct c_in, write h = o * c ----
__global__ void scan_p3(const float* __restrict__ gate, const _Float16* __restrict__ C,
                        const float* __restrict__ Cin, float* __restrict__ out) {
    int b = blockIdx.x >> 5;
    int nc = blockIdx.x & 31;
    int d = threadIdx.x;
    if (d >= D_SZ) return;
    size_t base = (size_t)b * T_SZ + (size_t)nc * CLEN;
    const float* gp = gate + base * D_SZ + d;
    const _Float16* zp = C + base * NP + d;
    const _Float16* op = zp + 320;
    float* hp = out + base * D_SZ + d;
    float c = Cin[(b * NCHUNK + nc) * D_SZ + d];
    for (int t = 0; t < CLEN; ++t) {
        float gv = gp[(size_t)t * D_SZ];
        float zv = (float)zp[(size_t)t * NP];
        float ov = (float)op[(size_t)t * NP];
        c = gv * c + (1.0f - gv) * zv;
        hp[(size_t)t * D_SZ] = ov * c;
    }
}

extern "C" void kernel_launch(void* const* d_in, const int* in_sizes, int n_in,
                              void* d_out, int out_size, void* d_ws, size_t ws_size,
                              hipStream_t stream) {
    const float* gate = (const float*)d_in[0];
    const float* xin  = (const float*)d_in[1];
    const float* Wz   = (const float*)d_in[2];
    const float* bz   = (const float*)d_in[3];
    const float* Wo   = (const float*)d_in[4];
    const float* bo   = (const float*)d_in[5];
    float* out = (float*)d_out;

    char* ws = (char*)d_ws;
    // workspace layout: Xf16 region is reused by scan summaries after the GEMM.
    _Float16* Xf16 = (_Float16*)(ws);                       // M*KP*2      = 83,886,080
    _Float16* C16  = (_Float16*)(ws + 83886080ull);         // M*NP*2      = 167,772,160
    _Float16* Wc   = (_Float16*)(ws + 251658240ull);        // NP*KP*2     = 409,600
    float*    bias = (float*)   (ws + 252067840ull);        // NP*4        = 2,560
    float*    Ach  = (float*)   (ws);                       // 64*32*300*4 = 2,457,600 (reuses Xf16)
    float*    Bch  = (float*)   (ws + 2457600ull);          // 2,457,600
    float*    Cin  = (float*)   (ws + 4915200ull);          // 2,457,600

    pack_x<<<(M_SZ * 80) / 256, 256, 0, stream>>>(xin, Xf16);
    pack_w<<<(NP * KP + 255) / 256, 256, 0, stream>>>(Wz, Wo, Wc);
    pack_bias<<<1, NP, 0, stream>>>(bz, bo, bias);

    gemm_zo<<<(M_SZ / 256) * (NP / 128), 512, 0, stream>>>(Xf16, Wc, bias, C16);

    scan_p1<<<B_SZ * NCHUNK, 320, 0, stream>>>(gate, C16, Ach, Bch);
    scan_p2<<<(B_SZ * D_SZ + 255) / 256, 256, 0, stream>>>(Ach, Bch, Cin);
    scan_p3<<<B_SZ * NCHUNK, 320, 0, stream>>>(gate, C16, Cin, out);
}